// Round 1
// baseline (170.683 us; speedup 1.0000x reference)
//
#include <hip/hip_runtime.h>
#include <math.h>

#define B 128
#define E 6
#define IN_DIM 1664
#define H_DIM 512
#define OUT_DIM 618
#define ZD 32
#define K2 (H_DIM + ZD)   // 544

// ---------------------------------------------------------------------------
// Partial GEMM:
//   part[split][b][n] = sum_e sum_{k in chunk(split)} x[b,k] * coef[b,e] * w[e,k,n]
// Block: 256 threads, output tile = 128 rows x 32 cols; loops over all E
// experts for its K-chunk. Non-atomic partial stores -> deterministic.
// a_s staged 8 k-values deep in LDS; ds_write is 2-way bank aliased (free),
// ds_read is broadcast across the 8 lanes of a column group.
// ---------------------------------------------------------------------------
template<bool NAL4>
__global__ __launch_bounds__(256) void moe_gemm_partial(
    const float* __restrict__ x,     // [B,K]
    const float* __restrict__ coef,  // [B,E]
    const float* __restrict__ w,     // [E,K,N]
    float* __restrict__ part,        // [S][B,N]
    int K, int N, int kchunk)
{
    const int nb    = blockIdx.x;
    const int split = blockIdx.y;
    const int n0    = nb * 32;
    const int k0    = split * kchunk;
    const int k1    = min(k0 + kchunk, K);

    const int tid  = threadIdx.x;
    const int tx   = tid & 7;        // 8 column groups of 4 cols
    const int ty   = tid >> 3;       // 32 row groups of 4 rows
    const int row0 = ty * 4;
    const int col0 = n0 + tx * 4;

    __shared__ float a_s[8][B];      // [kk][b] staged coef-weighted activations
    __shared__ float cf_s[B];

    float r[4][4];
    #pragma unroll
    for (int i = 0; i < 4; ++i)
        #pragma unroll
        for (int j = 0; j < 4; ++j) r[i][j] = 0.f;

    const int bld = tid >> 1;        // staging: row this thread loads
    const int kk4 = (tid & 1) * 4;   // staging: which 4 k's

    for (int e = 0; e < E; ++e) {
        __syncthreads();             // previous expert's staging reads done
        if (tid < B) cf_s[tid] = coef[tid * E + e];

        const float* wb = w + ((size_t)e * K) * N;

        for (int kb = k0; kb < k1; kb += 8) {
            __syncthreads();         // previous stage's a_s reads done / cf_s visible
            float4 xv = *reinterpret_cast<const float4*>(x + (size_t)bld * K + kb + kk4);
            const float c = cf_s[bld];
            a_s[kk4 + 0][bld] = xv.x * c;
            a_s[kk4 + 1][bld] = xv.y * c;
            a_s[kk4 + 2][bld] = xv.z * c;
            a_s[kk4 + 3][bld] = xv.w * c;
            __syncthreads();         // a_s visible

            #pragma unroll
            for (int kk = 0; kk < 8; ++kk) {
                const int k = kb + kk;
                float wv[4];
                if (NAL4) {
                    float4 t = *reinterpret_cast<const float4*>(wb + (size_t)k * N + col0);
                    wv[0] = t.x; wv[1] = t.y; wv[2] = t.z; wv[3] = t.w;
                } else {
                    #pragma unroll
                    for (int j = 0; j < 4; ++j) {
                        const int n = col0 + j;
                        wv[j] = (n < N) ? wb[(size_t)k * N + n] : 0.f;
                    }
                }
                float4 a4 = *reinterpret_cast<const float4*>(&a_s[kk][row0]);
                const float av[4] = {a4.x, a4.y, a4.z, a4.w};
                #pragma unroll
                for (int i = 0; i < 4; ++i)
                    #pragma unroll
                    for (int j = 0; j < 4; ++j)
                        r[i][j] = fmaf(av[i], wv[j], r[i][j]);
            }
        }
    }

    float* pb = part + (size_t)split * B * N;
    #pragma unroll
    for (int i = 0; i < 4; ++i) {
        const int row = row0 + i;
        if (NAL4) {
            float4 t;
            t.x = r[i][0]; t.y = r[i][1]; t.z = r[i][2]; t.w = r[i][3];
            *reinterpret_cast<float4*>(pb + (size_t)row * N + col0) = t;
        } else {
            #pragma unroll
            for (int j = 0; j < 4; ++j) {
                const int n = col0 + j;
                if (n < N) pb[(size_t)row * N + n] = r[i][j];
            }
        }
    }
}

// ---------------------------------------------------------------------------
// Reduce partials over S, add coef-blended bias, optional ELU, and append z
// (builds the next layer's concatenated input in one pass).
// ---------------------------------------------------------------------------
__global__ __launch_bounds__(256) void moe_finalize(
    const float* __restrict__ part,  // [S][B*N]
    const float* __restrict__ coef,  // [B,E]
    const float* __restrict__ bias,  // [E,N]
    const float* __restrict__ z,     // [B,ZD] (may be null when zd==0)
    float* __restrict__ out,         // [B, N+zd]
    int N, int S, int zd, int use_elu)
{
    const int idx = blockIdx.x * 256 + threadIdx.x;
    const int ostride = N + zd;
    if (idx >= B * ostride) return;
    const int b = idx / ostride;
    const int o = idx - b * ostride;

    if (o >= N) {                      // z pass-through columns
        out[idx] = z[b * ZD + (o - N)];
        return;
    }

    float v = 0.f;
    for (int s = 0; s < S; ++s)
        v += part[(size_t)s * B * N + (size_t)b * N + o];

    #pragma unroll
    for (int e = 0; e < E; ++e)
        v = fmaf(coef[b * E + e], bias[e * N + o], v);

    if (use_elu && v < 0.f) v = expm1f(v);   // elu(x), alpha=1
    out[idx] = v;
}

extern "C" void kernel_launch(void* const* d_in, const int* in_sizes, int n_in,
                              void* d_out, int out_size, void* d_ws, size_t ws_size,
                              hipStream_t stream)
{
    const float* p_prev = (const float*)d_in[0];
    const float* coef   = (const float*)d_in[1];
    const float* z      = (const float*)d_in[2];
    const float* w1     = (const float*)d_in[3];
    const float* b1     = (const float*)d_in[4];
    const float* w2     = (const float*)d_in[5];
    const float* b2     = (const float*)d_in[6];
    const float* w3     = (const float*)d_in[7];
    const float* b3     = (const float*)d_in[8];
    float* out = (float*)d_out;

    // ws layout (floats): partials (max 17*128*618 = 1,344,768) | x1 | x2
    float* part = (float*)d_ws;
    float* x1   = part + 1400000;          // [B, 544] = act(512) ++ z(32)
    float* x2   = x1 + B * K2;
    // total ~6.2 MB of workspace

    // L1: K=1664 per expert, N=512, S=16 splits of 104 (16*104 = 1664)
    moe_gemm_partial<true><<<dim3(16, 16), 256, 0, stream>>>(
        p_prev, coef, w1, part, IN_DIM, H_DIM, 104);
    moe_finalize<<<(B * K2 + 255) / 256, 256, 0, stream>>>(
        part, coef, b1, z, x1, H_DIM, 16, ZD, 1);

    // L2: K=544, N=512, S=17 splits of 32 (17*32 = 544)
    moe_gemm_partial<true><<<dim3(16, 17), 256, 0, stream>>>(
        x1, coef, w2, part, K2, H_DIM, 32);
    moe_finalize<<<(B * K2 + 255) / 256, 256, 0, stream>>>(
        part, coef, b2, z, x2, H_DIM, 17, ZD, 1);

    // L3: K=544, N=618 (not 16B-aligned per row -> scalar path), S=17
    moe_gemm_partial<false><<<dim3(20, 17), 256, 0, stream>>>(
        x2, coef, w3, part, K2, OUT_DIM, 32);
    moe_finalize<<<(B * OUT_DIM + 255) / 256, 256, 0, stream>>>(
        part, coef, b3, nullptr, out, OUT_DIM, 17, 0, 0);
}

// Round 2
// 89.957 us; speedup vs baseline: 1.8974x; 1.8974x over previous
//
#include <hip/hip_runtime.h>
#include <math.h>

#define B 128
#define E 6
#define IN_DIM 1664
#define H_DIM 512
#define OUT_DIM 618
#define ZD 32
#define K2 (H_DIM + ZD)   // 544

// ---------------------------------------------------------------------------
// Partial GEMM:
//   part[split][b][n] = sum_e sum_{k in chunk} x[b,k] * coef[b,e] * w[e,k,n]
// Block: 256 threads, tile = 128 rows x 32 cols, K-chunk = kchunk (mult of 8,
// divides K exactly). Per 8-k step: x staged coef-folded in a_s (all 256
// threads, 1 float4 each), w staged cooperatively in w_s (loaded ONCE per
// block, not per row-group). Non-atomic partial stores -> deterministic.
// All LDS patterns <=2-way bank aliased (free).
// ---------------------------------------------------------------------------
template<bool ALIGN4>
__global__ __launch_bounds__(256) void moe_gemm_partial(
    const float* __restrict__ x,     // [B,K]
    const float* __restrict__ coef,  // [B,E]
    const float* __restrict__ w,     // [E,K,N]
    float* __restrict__ part,        // [S][B,N]
    int K, int N, int kchunk)
{
    const int nb    = blockIdx.x;
    const int split = blockIdx.y;
    const int n0    = nb * 32;
    const int k0    = split * kchunk;

    const int tid  = threadIdx.x;
    const int tx   = tid & 7;        // 8 column groups of 4 cols
    const int ty   = tid >> 3;       // 32 row groups of 4 rows
    const int row0 = ty * 4;
    const int col0 = n0 + tx * 4;

    __shared__ float a_s[8][B];      // [kk][row] coef-folded activations
    __shared__ float w_s[8][32];     // [kk][n]   weight tile

    // staging assignment: this thread stages row bld, k's [kb+kk4, kb+kk4+4)
    const int bld = tid >> 1;
    const int kk4 = (tid & 1) * 4;

    float ce[E];
    #pragma unroll
    for (int e = 0; e < E; ++e) ce[e] = coef[bld * E + e];

    float r[4][4];
    #pragma unroll
    for (int i = 0; i < 4; ++i)
        #pragma unroll
        for (int j = 0; j < 4; ++j) r[i][j] = 0.f;

    for (int e = 0; e < E; ++e) {
        const float* wb = w + ((size_t)e * K) * N;
        const float c = ce[e];

        for (int kb = k0; kb < k0 + kchunk; kb += 8) {
            __syncthreads();         // previous step's LDS reads done
            // ---- stage x (coef-folded) ----
            float4 xv = *reinterpret_cast<const float4*>(x + (size_t)bld * K + kb + kk4);
            a_s[kk4 + 0][bld] = xv.x * c;
            a_s[kk4 + 1][bld] = xv.y * c;
            a_s[kk4 + 2][bld] = xv.z * c;
            a_s[kk4 + 3][bld] = xv.w * c;
            // ---- stage w (once per block) ----
            if (ALIGN4) {
                if (tid < 64) {      // 64 float4 = 8k x 32n
                    const int kk = tid >> 3, n4 = (tid & 7) * 4;
                    float4 wv = *reinterpret_cast<const float4*>(
                        wb + (size_t)(kb + kk) * N + n0 + n4);
                    *reinterpret_cast<float4*>(&w_s[kk][n4]) = wv;
                }
            } else {                 // scalar, bounds-checked (N=618 path)
                const int kk = tid >> 5, n = tid & 31;
                const int col = n0 + n;
                w_s[kk][n] = (col < N) ? wb[(size_t)(kb + kk) * N + col] : 0.f;
            }
            __syncthreads();         // stages visible

            #pragma unroll
            for (int kk = 0; kk < 8; ++kk) {
                float4 a4 = *reinterpret_cast<const float4*>(&a_s[kk][row0]);
                float4 w4 = *reinterpret_cast<const float4*>(&w_s[kk][tx * 4]);
                const float av[4] = {a4.x, a4.y, a4.z, a4.w};
                const float wv[4] = {w4.x, w4.y, w4.z, w4.w};
                #pragma unroll
                for (int i = 0; i < 4; ++i)
                    #pragma unroll
                    for (int j = 0; j < 4; ++j)
                        r[i][j] = fmaf(av[i], wv[j], r[i][j]);
            }
        }
    }

    float* pb = part + (size_t)split * B * N;
    #pragma unroll
    for (int i = 0; i < 4; ++i) {
        const int row = row0 + i;
        if (ALIGN4) {
            float4 t;
            t.x = r[i][0]; t.y = r[i][1]; t.z = r[i][2]; t.w = r[i][3];
            *reinterpret_cast<float4*>(pb + (size_t)row * N + col0) = t;
        } else {
            #pragma unroll
            for (int j = 0; j < 4; ++j) {
                const int n = col0 + j;
                if (n < N) pb[(size_t)row * N + n] = r[i][j];
            }
        }
    }
}

// ---------------------------------------------------------------------------
// Reduce partials over S, add coef-blended bias, optional ELU, append z.
// ---------------------------------------------------------------------------
__global__ __launch_bounds__(256) void moe_finalize(
    const float* __restrict__ part,  // [S][B*N]
    const float* __restrict__ coef,  // [B,E]
    const float* __restrict__ bias,  // [E,N]
    const float* __restrict__ z,     // [B,ZD] (may be null when zd==0)
    float* __restrict__ out,         // [B, N+zd]
    int N, int S, int zd, int use_elu)
{
    const int idx = blockIdx.x * 256 + threadIdx.x;
    const int ostride = N + zd;
    if (idx >= B * ostride) return;
    const int b = idx / ostride;
    const int o = idx - b * ostride;

    if (o >= N) {                    // z pass-through columns
        out[idx] = z[b * ZD + (o - N)];
        return;
    }

    float v = 0.f;
    #pragma unroll 4
    for (int s = 0; s < S; ++s)
        v += part[(size_t)s * B * N + (size_t)b * N + o];

    #pragma unroll
    for (int e = 0; e < E; ++e)
        v = fmaf(coef[b * E + e], bias[e * N + o], v);

    if (use_elu && v < 0.f) v = expm1f(v);   // elu(x), alpha=1
    out[idx] = v;
}

extern "C" void kernel_launch(void* const* d_in, const int* in_sizes, int n_in,
                              void* d_out, int out_size, void* d_ws, size_t ws_size,
                              hipStream_t stream)
{
    const float* p_prev = (const float*)d_in[0];
    const float* coef   = (const float*)d_in[1];
    const float* z      = (const float*)d_in[2];
    const float* w1     = (const float*)d_in[3];
    const float* b1     = (const float*)d_in[4];
    const float* w2     = (const float*)d_in[5];
    const float* b2     = (const float*)d_in[6];
    const float* w3     = (const float*)d_in[7];
    const float* b3     = (const float*)d_in[8];
    float* out = (float*)d_out;

    // Runtime tiering on ws_size: finer K-splits -> more blocks/CU.
    // kchunks must divide K exactly and be multiples of 8.
    int kc1, kc23;
    {
        const size_t nf = ws_size / sizeof(float);
        const size_t xbuf = 2 * (size_t)B * K2;
        // tier A: L1 S=52, L2/L3 S=34
        size_t needA = (size_t)52 * B * H_DIM + xbuf;   // L3 part 34*B*OUT smaller
        size_t partA34 = (size_t)34 * B * OUT_DIM;
        if (partA34 + xbuf > needA) needA = partA34 + xbuf;
        // tier B: L1 S=26, L2/L3 S=17
        size_t needB = (size_t)26 * B * H_DIM + xbuf;
        size_t partB17 = (size_t)17 * B * OUT_DIM;
        if (partB17 + xbuf > needB) needB = partB17 + xbuf;

        if (nf >= needA)      { kc1 = 32;  kc23 = 16; }
        else if (nf >= needB) { kc1 = 64;  kc23 = 32; }
        else                  { kc1 = 104; kc23 = 32; }  // round-0 footprint
    }
    const int S1  = IN_DIM / kc1;   // 52 / 26 / 16
    const int S23 = K2 / kc23;      // 34 / 17

    // ws layout (floats): part | x1 | x2
    size_t maxPart = (size_t)S1 * B * H_DIM;
    size_t p3 = (size_t)S23 * B * OUT_DIM;
    if (p3 > maxPart) maxPart = p3;

    float* part = (float*)d_ws;
    float* x1   = part + maxPart;       // [B, 544] = act(512) ++ z(32)
    float* x2   = x1 + (size_t)B * K2;

    // L1: K=1664, N=512
    moe_gemm_partial<true><<<dim3(16, S1), 256, 0, stream>>>(
        p_prev, coef, w1, part, IN_DIM, H_DIM, kc1);
    moe_finalize<<<(B * K2 + 255) / 256, 256, 0, stream>>>(
        part, coef, b1, z, x1, H_DIM, S1, ZD, 1);

    // L2: K=544, N=512
    moe_gemm_partial<true><<<dim3(16, S23), 256, 0, stream>>>(
        x1, coef, w2, part, K2, H_DIM, kc23);
    moe_finalize<<<(B * K2 + 255) / 256, 256, 0, stream>>>(
        part, coef, b2, z, x2, H_DIM, S23, ZD, 1);

    // L3: K=544, N=618 (row stride not 16B-aligned -> scalar w staging)
    moe_gemm_partial<false><<<dim3((OUT_DIM + 31) / 32, S23), 256, 0, stream>>>(
        x2, coef, w3, part, K2, OUT_DIM, kc23);
    moe_finalize<<<(B * OUT_DIM + 255) / 256, 256, 0, stream>>>(
        part, coef, b3, nullptr, out, OUT_DIM, S23, 0, 0);
}